// Round 2
// baseline (119.617 us; speedup 1.0000x reference)
//
#include <hip/hip_runtime.h>
#include <hip/hip_bf16.h>

// ---------------------------------------------------------------------------
// ParticleQAEEncoder.
// Jet (n=10, 1024 amps, depth 4) now uses 128 threads (2 waves) per event,
// 8 complex amps per lane, to double wave count (occupancy was 27%) and
// halve the per-wave dependent shuffle chain.
//
// Index mapping (wire k <-> idx bit 9-k):
//   idx bits 9..7 = reg bits 2..0      (wires 0,1,2  - latent)
//   idx bits 6..4 = lane bits 5..3     (wires 3,4,5  - latent)
//   idx bit  3    = wave bit w         (wire 6       - trash)
//   idx bits 2..0 = lane bits 2..0     (wires 7,8,9  - trash)
// P1 (flip latent iff parity(trash)) is wave-local: lane^0x38, r^7.
// P2 (flip trash iff parity(latent)) + wire-6 RY fused into ONE LDS
// round-trip per depth:
//   st'  = c*st + sg*q                      (RY6; q = other wave, same lane)
//   mov  = c*shfl7(q) - sg*shfl7(st)        (= st' at (w^1, lane^7))
//   st'' = pl ? mov : st'
// ---------------------------------------------------------------------------

struct cplx { float re, im; };

__device__ __forceinline__ cplx cmul(cplx a, cplx b) {
  cplx r; r.re = a.re*b.re - a.im*b.im; r.im = a.re*b.im + a.im*b.re; return r;
}
__device__ __forceinline__ cplx csel(int c, cplx a, cplx b) {
  cplx r; r.re = c ? a.re : b.re; r.im = c ? a.im : b.im; return r;
}
__device__ __forceinline__ cplx shflx(cplx v, int m) {
  cplx r; r.re = __shfl_xor(v.re, m, 64); r.im = __shfl_xor(v.im, m, 64); return r;
}

// |0>-column of RZ(phi)*RY(pt)*RX(eta)  (applied RX,RY,RZ order)
__device__ __forceinline__ void enc_col(float pt, float eta, float phi,
                                        cplx* A, cplx* Bq) {
  float cx = __cosf(0.5f*eta), sx = __sinf(0.5f*eta);
  float cy = __cosf(0.5f*pt),  sy = __sinf(0.5f*pt);
  float cz = __cosf(0.5f*phi), sz = __sinf(0.5f*phi);
  float u = cy*cx, v = sy*sx;
  float p = sy*cx, q = -cy*sx;
  A->re  = cz*u + sz*v;  A->im  = cz*v - sz*u;
  Bq->re = cz*p - sz*q;  Bq->im = cz*q + sz*p;
}

// ---------------- ele/mu: n=4, 16 amps per thread, depth 1 ----------------
__device__ void sim4(const float* __restrict__ pt, const float* __restrict__ eta,
                     const float* __restrict__ phi, const float* __restrict__ w,
                     float* z_w2, float* z_w3) {
  cplx A[4], Bw[4];
  #pragma unroll
  for (int k = 0; k < 4; ++k)
    enc_col(pt[k], eta[k], phi[k], &A[k], &Bw[k]);

  cplx st[16];
  #pragma unroll
  for (int i = 0; i < 16; ++i) {
    cplx f = csel((i>>3)&1, Bw[0], A[0]);
    f = cmul(f, csel((i>>2)&1, Bw[1], A[1]));
    f = cmul(f, csel((i>>1)&1, Bw[2], A[2]));
    f = cmul(f, csel( i    &1, Bw[3], A[3]));
    st[i] = f;
  }
  cplx t;
  t = st[1]; st[1] = st[13]; st[13] = t;
  t = st[2]; st[2] = st[14]; st[14] = t;
  t = st[5]; st[5] = st[9];  st[9]  = t;
  t = st[6]; st[6] = st[10]; st[10] = t;
  #pragma unroll
  for (int k = 0; k < 4; ++k) {
    float a5 = 0.5f * w[k];
    float c = __cosf(a5), s = __sinf(a5);
    const int m = 8 >> k;
    #pragma unroll
    for (int i = 0; i < 16; ++i) {
      if (!(i & m)) {
        cplx a = st[i], bb = st[i|m];
        st[i].re   = c*a.re - s*bb.re;  st[i].im   = c*a.im - s*bb.im;
        st[i|m].re = s*a.re + c*bb.re;  st[i|m].im = s*a.im + c*bb.im;
      }
    }
  }
  t = st[4]; st[4] = st[7];  st[7]  = t;
  t = st[5]; st[5] = st[6];  st[6]  = t;
  t = st[8]; st[8] = st[11]; st[11] = t;
  t = st[9]; st[9] = st[10]; st[10] = t;

  float z2 = 0.f, z3 = 0.f;
  #pragma unroll
  for (int i = 0; i < 16; ++i) {
    float p = st[i].re*st[i].re + st[i].im*st[i].im;
    z2 += ((i>>1)&1) ? -p : p;
    z3 += ( i    &1) ? -p : p;
  }
  *z_w2 = z2; *z_w3 = z3;
}

__global__ __launch_bounds__(128)
void qae_kernel(const float* __restrict__ x,
                const float* __restrict__ met_w,
                const float* __restrict__ ele_w,
                const float* __restrict__ mu_w,
                const float* __restrict__ jet_w,
                float* __restrict__ out, int B) {
  __shared__ float sm[128*18 + 16];
  if ((int)blockIdx.x < B) {
    const int b    = blockIdx.x;
    const int tid  = threadIdx.x;      // 0..127
    const int lane = tid & 63;
    const int w    = tid >> 6;         // wave bit = wire 6 (trash)
    const float* xr = x + (size_t)b*56;

    cplx A[10], Bw[10];
    #pragma unroll
    for (int k = 0; k < 10; ++k)
      enc_col(xr[26+k], xr[36+k], xr[46+k], &A[k], &Bw[k]);

    // per-thread product factor over wires 3..9
    cplx lf = csel((lane>>5)&1, Bw[3], A[3]);
    lf = cmul(lf, csel((lane>>4)&1, Bw[4], A[4]));
    lf = cmul(lf, csel((lane>>3)&1, Bw[5], A[5]));
    lf = cmul(lf, csel(w,           Bw[6], A[6]));
    lf = cmul(lf, csel((lane>>2)&1, Bw[7], A[7]));
    lf = cmul(lf, csel((lane>>1)&1, Bw[8], A[8]));
    lf = cmul(lf, csel( lane    &1, Bw[9], A[9]));

    cplx st[8];
    #pragma unroll
    for (int r = 0; r < 8; ++r) {
      cplx f = cmul(lf, csel((r>>2)&1, Bw[0], A[0]));
      f = cmul(f, csel((r>>1)&1, Bw[1], A[1]));
      f = cmul(f, csel( r    &1, Bw[2], A[2]));
      st[r] = f;
    }

    const int pt_par  = (__popc(lane & 7) + w) & 1;   // parity of trash bits
    const int pl_lane = __popc((lane>>3) & 7) & 1;    // latent lane-bit parity
    float2* myb = (float2*)(sm + tid*18);
    float2* pb  = (float2*)(sm + (tid^64)*18);

    #pragma unroll
    for (int d = 0; d < 4; ++d) {
      // P1: flip latent (lane^0x38, r^7) iff parity(trash)
      #pragma unroll
      for (int r = 0; r < 4; ++r) {
        cplx v1 = st[r], v2 = st[r^7];
        cplx o1 = shflx(v2, 0x38), o2 = shflx(v1, 0x38);
        st[r]   = csel(pt_par, o1, v1);
        st[r^7] = csel(pt_par, o2, v2);
      }
      float c[10], s[10];
      #pragma unroll
      for (int k = 0; k < 10; ++k) {
        float a = 0.5f * jet_w[d*10 + k];
        c[k] = __cosf(a); s[k] = __sinf(a);
      }
      // wires 0..2: register-pair (r bits 2,1,0)
      #pragma unroll
      for (int k = 0; k < 3; ++k) {
        const int mr = 4 >> k;
        #pragma unroll
        for (int r = 0; r < 8; ++r) {
          if (!(r & mr)) {
            cplx a = st[r], bb = st[r|mr];
            st[r].re    = c[k]*a.re - s[k]*bb.re;
            st[r].im    = c[k]*a.im - s[k]*bb.im;
            st[r|mr].re = s[k]*a.re + c[k]*bb.re;
            st[r|mr].im = s[k]*a.im + c[k]*bb.im;
          }
        }
      }
      // wires 3,4,5 (lane bits 5,4,3) and 7,8,9 (lane bits 2,1,0)
      #pragma unroll
      for (int kk = 0; kk < 6; ++kk) {
        const int k  = (kk < 3) ? (3 + kk) : (4 + kk);     // 3,4,5,7,8,9
        const int lm = (kk < 3) ? (32 >> kk) : (4 >> (kk-3));
        const float sg = (lane & lm) ? s[k] : -s[k];
        #pragma unroll
        for (int r = 0; r < 8; ++r) {
          cplx o = shflx(st[r], lm);
          st[r].re = c[k]*st[r].re + sg*o.re;
          st[r].im = c[k]*st[r].im + sg*o.im;
        }
      }
      // fused wire-6 RY + P2 (one LDS round-trip)
      #pragma unroll
      for (int r = 0; r < 8; ++r) myb[r] = make_float2(st[r].re, st[r].im);
      __syncthreads();
      cplx q[8];
      #pragma unroll
      for (int r = 0; r < 8; ++r) { float2 v = pb[r]; q[r].re = v.x; q[r].im = v.y; }
      __syncthreads();
      const float sg6 = w ? s[6] : -s[6];
      #pragma unroll
      for (int r = 0; r < 8; ++r) {
        cplx keep;
        keep.re = c[6]*st[r].re + sg6*q[r].re;
        keep.im = c[6]*st[r].im + sg6*q[r].im;
        cplx qs = shflx(q[r], 7), ss = shflx(st[r], 7);
        cplx mov;
        mov.re = c[6]*qs.re - sg6*ss.re;
        mov.im = c[6]*qs.im - sg6*ss.im;
        const int pl = (pl_lane + __popc(r)) & 1;
        st[r] = csel(pl, mov, keep);
      }
    }

    // expectations on trash wires
    float pr = 0.f;
    #pragma unroll
    for (int r = 0; r < 8; ++r) pr += st[r].re*st[r].re + st[r].im*st[r].im;
    pr += __shfl_xor(pr, 8, 64);    // latent lane bits
    pr += __shfl_xor(pr, 16, 64);
    pr += __shfl_xor(pr, 32, 64);
    float y = pr;                    // WHT over trash lane bits 0..2
    #pragma unroll
    for (int j = 1; j <= 4; j <<= 1) {
      float aa = __shfl_xor(y, j, 64);
      y = (lane & j) ? (aa - y) : (y + aa);
    }
    float* red = sm + 128*18;
    if (lane < 8) red[w*8 + lane] = y;
    __syncthreads();
    if (tid == 0) {
      float* o = out + (size_t)5*B + (size_t)b*4;
      o[0] = red[0] - red[8];        // wire 6: sign = wave bit
      o[1] = red[4] + red[12];       // wire 7: lane bit 2
      o[2] = red[2] + red[10];       // wire 8: lane bit 1
      o[3] = red[1] + red[9];        // wire 9: lane bit 0
    }
  } else {
    int b = ((int)blockIdx.x - B) * 128 + threadIdx.x;
    if (b >= B) return;
    const float* xr = x + (size_t)b*56;
    // ---- met: n=1 analytic ----
    {
      float pt = xr[0], phi = xr[1], mw = met_w[0];
      float cy = __cosf(0.5f*pt),  sy = __sinf(0.5f*pt);
      float cz = __cosf(0.5f*phi), sz = __sinf(0.5f*phi);
      float cw = __cosf(0.5f*mw),  sw = __sinf(0.5f*mw);
      cplx al; al.re = cz*cy; al.im = -sz*cy;
      cplx be; be.re = cz*sy; be.im =  sz*sy;
      cplx a0; a0.re = cw*al.re - sw*be.re; a0.im = cw*al.im - sw*be.im;
      cplx a1; a1.re = sw*al.re + cw*be.re; a1.im = sw*al.im + cw*be.im;
      out[b] = (a0.re*a0.re + a0.im*a0.im) - (a1.re*a1.re + a1.im*a1.im);
    }
    float z2, z3;
    sim4(xr+2,  xr+6,  xr+10, ele_w, &z2, &z3);
    out[B   + b*2 + 0] = z2;  out[B   + b*2 + 1] = z3;
    sim4(xr+14, xr+18, xr+22, mu_w, &z2, &z3);
    out[3*B + b*2 + 0] = z2;  out[3*B + b*2 + 1] = z3;
  }
}

extern "C" void kernel_launch(void* const* d_in, const int* in_sizes, int n_in,
                              void* d_out, int out_size, void* d_ws, size_t ws_size,
                              hipStream_t stream) {
  const float* x     = (const float*)d_in[0];
  const float* met_w = (const float*)d_in[1];
  const float* ele_w = (const float*)d_in[2];
  const float* mu_w  = (const float*)d_in[3];
  const float* jet_w = (const float*)d_in[4];
  float* out = (float*)d_out;
  int B = in_sizes[0] / 56;
  int jet_blocks   = B;                      // 128 threads (2 waves) per event
  int small_blocks = (B + 127) / 128;        // one thread per event
  qae_kernel<<<dim3(jet_blocks + small_blocks), dim3(128), 0, stream>>>(
      x, met_w, ele_w, mu_w, jet_w, out, B);
}

// Round 3
// 85.360 us; speedup vs baseline: 1.4013x; 1.4013x over previous
//
#include <hip/hip_runtime.h>
#include <hip/hip_bf16.h>

// ---------------------------------------------------------------------------
// ParticleQAEEncoder.
// Jet (n=10, 1024 amps, depth 4): ONE wave per event, 16 cplx amps/lane.
// Mapping (wire k <-> idx bit 9-k):
//   latent wires 0..5 -> lane bits 5..0 (shuffle masks 32,16,8,4,2,1)
//   trash  wires 6..9 -> reg  bits 3..0
// Why this mapping:
//   P1 (flip latent iff parity(trash)): parity(r) is compile-time -> only the
//      8 odd-parity regs get shfl_xor(63); no cndmask.            [16 DS ops]
//   P2 (flip trash iff parity(latent)): pure register permutation + cndmask
//      on per-lane parity.                                        [0 DS ops]
//   RY masks 1,2 = DPP quad_perm; 8 = DPP row_ror:8; 4 = 2 masked-bank DPPs
//      (VALU pipe, no DS); only masks 16 (ds_swizzle) and 32 (ds_bpermute)
//      touch the DS pipe.                                 [64 DS ops / depth]
// Round-1 had 256 DS ops/depth -> now 80. No LDS, no barriers.
// ---------------------------------------------------------------------------

struct cplx { float re, im; };

__device__ __forceinline__ cplx cmul(cplx a, cplx b) {
  cplx r; r.re = a.re*b.re - a.im*b.im; r.im = a.re*b.im + a.im*b.re; return r;
}
__device__ __forceinline__ cplx csel(int c, cplx a, cplx b) {
  cplx r; r.re = c ? a.re : b.re; r.im = c ? a.im : b.im; return r;
}

// ---- cross-lane helpers ----
template<int CTRL, int ROW, int BANK, bool BC>
__device__ __forceinline__ float dppf(float oldv, float v) {
  return __int_as_float(__builtin_amdgcn_update_dpp(
      __float_as_int(oldv), __float_as_int(v), CTRL, ROW, BANK, BC));
}
__device__ __forceinline__ float xor1f(float v) { return dppf<0xB1, 0xF, 0xF, true>(v, v); }   // quad_perm [1,0,3,2]
__device__ __forceinline__ float xor2f(float v) { return dppf<0x4E, 0xF, 0xF, true>(v, v); }   // quad_perm [2,3,0,1]
__device__ __forceinline__ float xor8f(float v) { return dppf<0x128, 0xF, 0xF, true>(v, v); }  // row_ror:8 == xor8 in 16-row
__device__ __forceinline__ float xor4f(float v) {
  float t = dppf<0x104, 0xF, 0xA, false>(v, v);   // row_shl:4 into banks 1,3
  return    dppf<0x114, 0xF, 0x5, false>(t, v);   // row_shr:4 into banks 0,2
}
__device__ __forceinline__ float xor16f(float v) {
  return __int_as_float(__builtin_amdgcn_ds_swizzle(__float_as_int(v), 0x401F)); // xor16 within 32-half
}
__device__ __forceinline__ float bpermf(int addr, float v) {
  return __int_as_float(__builtin_amdgcn_ds_bpermute(addr, __float_as_int(v)));
}

// |0>-column of RZ(phi)*RY(pt)*RX(eta)  (applied RX,RY,RZ order)
__device__ __forceinline__ void enc_col(float pt, float eta, float phi,
                                        cplx* A, cplx* Bq) {
  float cx = __cosf(0.5f*eta), sx = __sinf(0.5f*eta);
  float cy = __cosf(0.5f*pt),  sy = __sinf(0.5f*pt);
  float cz = __cosf(0.5f*phi), sz = __sinf(0.5f*phi);
  float u = cy*cx, v = sy*sx;
  float p = sy*cx, q = -cy*sx;
  A->re  = cz*u + sz*v;  A->im  = cz*v - sz*u;
  Bq->re = cz*p - sz*q;  Bq->im = cz*q + sz*p;
}

// ---------------- jet: one wave per event ----------------
__device__ void jet_sim(const float* __restrict__ xr, const float* __restrict__ jw,
                        float* __restrict__ out, int b, int lane, int B) {
  cplx A[10], Bw[10];
  #pragma unroll
  for (int k = 0; k < 10; ++k)
    enc_col(xr[26+k], xr[36+k], xr[46+k], &A[k], &Bw[k]);

  // lane factor over wires 0..5 (lane bit 5-w)
  cplx f = csel((lane>>5)&1, Bw[0], A[0]);
  f = cmul(f, csel((lane>>4)&1, Bw[1], A[1]));
  f = cmul(f, csel((lane>>3)&1, Bw[2], A[2]));
  f = cmul(f, csel((lane>>2)&1, Bw[3], A[3]));
  f = cmul(f, csel((lane>>1)&1, Bw[4], A[4]));
  f = cmul(f, csel( lane    &1, Bw[5], A[5]));

  // product tree over reg bits: r = (b6<<3)|(b7<<2)|(b8<<1)|b9
  cplx st[16];
  {
    cplx h6[2]; h6[0] = cmul(f, A[6]); h6[1] = cmul(f, Bw[6]);
    cplx h7[4];
    #pragma unroll
    for (int j = 0; j < 2; ++j) { h7[2*j] = cmul(h6[j], A[7]); h7[2*j+1] = cmul(h6[j], Bw[7]); }
    cplx h8[8];
    #pragma unroll
    for (int j = 0; j < 4; ++j) { h8[2*j] = cmul(h7[j], A[8]); h8[2*j+1] = cmul(h7[j], Bw[8]); }
    #pragma unroll
    for (int j = 0; j < 8; ++j) { st[2*j] = cmul(h8[j], A[9]); st[2*j+1] = cmul(h8[j], Bw[9]); }
  }

  const int a63 = (lane ^ 63) << 2;       // bpermute byte addr for xor63
  const int a32 = (lane ^ 32) << 2;       // bpermute byte addr for xor32
  const int pl  = __popc(lane) & 1;       // parity of latent (all lane bits)

  #pragma unroll
  for (int d = 0; d < 4; ++d) {
    float c[10], s[10];
    #pragma unroll
    for (int k = 0; k < 10; ++k) __sincosf(0.5f * jw[d*10 + k], &s[k], &c[k]);

    // P1: flip all latent (lane^63) iff parity(trash)=parity(r) (compile-time)
    #pragma unroll
    for (int r = 0; r < 16; ++r) {
      if (__popc(r) & 1) {
        st[r].re = bpermf(a63, st[r].re);
        st[r].im = bpermf(a63, st[r].im);
      }
    }

    // RY on lane wires 0..5 (masks 32,16,8,4,2,1)
#define LANE_RY(K, M, SHUF)                                   \
    { const float cc = c[K];                                  \
      const float sg = (lane & (M)) ? s[K] : -s[K];           \
      _Pragma("unroll")                                       \
      for (int r = 0; r < 16; ++r) {                          \
        float ore = SHUF(st[r].re), oim = SHUF(st[r].im);     \
        st[r].re = cc*st[r].re + sg*ore;                      \
        st[r].im = cc*st[r].im + sg*oim;                      \
      } }
#define SH32(v) bpermf(a32, v)
    LANE_RY(0, 32, SH32)
    LANE_RY(1, 16, xor16f)
    LANE_RY(2,  8, xor8f)
    LANE_RY(3,  4, xor4f)
    LANE_RY(4,  2, xor2f)
    LANE_RY(5,  1, xor1f)
#undef SH32
#undef LANE_RY

    // RY on reg wires 6..9 (reg bit 9-k)
    #pragma unroll
    for (int k = 6; k < 10; ++k) {
      const int mr = 1 << (9-k);
      #pragma unroll
      for (int r = 0; r < 16; ++r) {
        if (!(r & mr)) {
          cplx a = st[r], bb = st[r|mr];
          st[r].re    = c[k]*a.re - s[k]*bb.re;
          st[r].im    = c[k]*a.im - s[k]*bb.im;
          st[r|mr].re = s[k]*a.re + c[k]*bb.re;
          st[r|mr].im = s[k]*a.im + c[k]*bb.im;
        }
      }
    }

    // P2: flip trash (reg bits, r^15) iff parity(latent lanes) — no shuffles
    #pragma unroll
    for (int r = 0; r < 8; ++r) {
      cplx a = st[r], bb = st[r^15];
      st[r]    = csel(pl, bb, a);
      st[r^15] = csel(pl, a, bb);
    }
  }

  // <Z> on trash wires 6..9 = reg bits 3..0; sum over all lanes
  float z0 = 0.f, z1 = 0.f, z2 = 0.f, z3 = 0.f;
  #pragma unroll
  for (int r = 0; r < 16; ++r) {
    float p = st[r].re*st[r].re + st[r].im*st[r].im;
    z0 += (r & 8) ? -p : p;
    z1 += (r & 4) ? -p : p;
    z2 += (r & 2) ? -p : p;
    z3 += (r & 1) ? -p : p;
  }
  #pragma unroll
  for (int j = 1; j <= 32; j <<= 1) {
    z0 += __shfl_xor(z0, j, 64);
    z1 += __shfl_xor(z1, j, 64);
    z2 += __shfl_xor(z2, j, 64);
    z3 += __shfl_xor(z3, j, 64);
  }
  if (lane == 0) {
    float* o = out + (size_t)5*B + (size_t)b*4;
    o[0] = z0; o[1] = z1; o[2] = z2; o[3] = z3;
  }
}

// ---------------- ele/mu: n=4, 16 amps per thread, depth 1 ----------------
__device__ void sim4(const float* __restrict__ pt, const float* __restrict__ eta,
                     const float* __restrict__ phi, const float* __restrict__ w,
                     float* z_w2, float* z_w3) {
  cplx A[4], Bw[4];
  #pragma unroll
  for (int k = 0; k < 4; ++k)
    enc_col(pt[k], eta[k], phi[k], &A[k], &Bw[k]);

  cplx st[16];
  #pragma unroll
  for (int i = 0; i < 16; ++i) {
    cplx f = csel((i>>3)&1, Bw[0], A[0]);
    f = cmul(f, csel((i>>2)&1, Bw[1], A[1]));
    f = cmul(f, csel((i>>1)&1, Bw[2], A[2]));
    f = cmul(f, csel( i    &1, Bw[3], A[3]));
    st[i] = f;
  }
  cplx t;
  t = st[1]; st[1] = st[13]; st[13] = t;
  t = st[2]; st[2] = st[14]; st[14] = t;
  t = st[5]; st[5] = st[9];  st[9]  = t;
  t = st[6]; st[6] = st[10]; st[10] = t;
  #pragma unroll
  for (int k = 0; k < 4; ++k) {
    float a5 = 0.5f * w[k];
    float c = __cosf(a5), s = __sinf(a5);
    const int m = 8 >> k;
    #pragma unroll
    for (int i = 0; i < 16; ++i) {
      if (!(i & m)) {
        cplx a = st[i], bb = st[i|m];
        st[i].re   = c*a.re - s*bb.re;  st[i].im   = c*a.im - s*bb.im;
        st[i|m].re = s*a.re + c*bb.re;  st[i|m].im = s*a.im + c*bb.im;
      }
    }
  }
  t = st[4]; st[4] = st[7];  st[7]  = t;
  t = st[5]; st[5] = st[6];  st[6]  = t;
  t = st[8]; st[8] = st[11]; st[11] = t;
  t = st[9]; st[9] = st[10]; st[10] = t;

  float z2 = 0.f, z3 = 0.f;
  #pragma unroll
  for (int i = 0; i < 16; ++i) {
    float p = st[i].re*st[i].re + st[i].im*st[i].im;
    z2 += ((i>>1)&1) ? -p : p;
    z3 += ( i    &1) ? -p : p;
  }
  *z_w2 = z2; *z_w3 = z3;
}

__global__ __launch_bounds__(256, 4)
void qae_kernel(const float* __restrict__ x,
                const float* __restrict__ met_w,
                const float* __restrict__ ele_w,
                const float* __restrict__ mu_w,
                const float* __restrict__ jet_w,
                float* __restrict__ out, int B, int jet_blocks) {
  if ((int)blockIdx.x < jet_blocks) {
    int b = blockIdx.x * 4 + (threadIdx.x >> 6);   // one wave per event
    int lane = threadIdx.x & 63;
    if (b < B)
      jet_sim(x + (size_t)b*56, jet_w, out, b, lane, B);
  } else {
    int b = ((int)blockIdx.x - jet_blocks) * 256 + threadIdx.x;
    if (b >= B) return;
    const float* xr = x + (size_t)b*56;
    // ---- met: n=1 analytic ----
    {
      float pt = xr[0], phi = xr[1], mw = met_w[0];
      float cy = __cosf(0.5f*pt),  sy = __sinf(0.5f*pt);
      float cz = __cosf(0.5f*phi), sz = __sinf(0.5f*phi);
      float cw = __cosf(0.5f*mw),  sw = __sinf(0.5f*mw);
      cplx al; al.re = cz*cy; al.im = -sz*cy;
      cplx be; be.re = cz*sy; be.im =  sz*sy;
      cplx a0; a0.re = cw*al.re - sw*be.re; a0.im = cw*al.im - sw*be.im;
      cplx a1; a1.re = sw*al.re + cw*be.re; a1.im = sw*al.im + cw*be.im;
      out[b] = (a0.re*a0.re + a0.im*a0.im) - (a1.re*a1.re + a1.im*a1.im);
    }
    float z2, z3;
    sim4(xr+2,  xr+6,  xr+10, ele_w, &z2, &z3);
    out[B   + b*2 + 0] = z2;  out[B   + b*2 + 1] = z3;
    sim4(xr+14, xr+18, xr+22, mu_w, &z2, &z3);
    out[3*B + b*2 + 0] = z2;  out[3*B + b*2 + 1] = z3;
  }
}

extern "C" void kernel_launch(void* const* d_in, const int* in_sizes, int n_in,
                              void* d_out, int out_size, void* d_ws, size_t ws_size,
                              hipStream_t stream) {
  const float* x     = (const float*)d_in[0];
  const float* met_w = (const float*)d_in[1];
  const float* ele_w = (const float*)d_in[2];
  const float* mu_w  = (const float*)d_in[3];
  const float* jet_w = (const float*)d_in[4];
  float* out = (float*)d_out;
  int B = in_sizes[0] / 56;
  int jet_blocks   = (B + 3) / 4;            // one wave (64 lanes) per event
  int small_blocks = (B + 255) / 256;        // one thread per event
  qae_kernel<<<dim3(jet_blocks + small_blocks), dim3(256), 0, stream>>>(
      x, met_w, ele_w, mu_w, jet_w, out, B, jet_blocks);
}